// Round 7
// baseline (234.334 us; speedup 1.0000x reference)
//
#include <hip/hip_runtime.h>

// RollScheduler forward: out[b,c,k] = clips[b,c,k-idx] for k>=idx else 0,
// idx = trunc(x[b,c] * N). Pure memory-bound shift-right per row.
// B=C=32, N=32768, fp32. `actual` input is unused in forward.
//
// R3 lesson: per-lane float4 chunks with 4 scalar dword loads are stride-16B
// per instruction (16 lines/instr, 4B used per line) -> VMEM-inefficient.
// Fix: load the TWO aligned float4s straddling each lane's source window
// (both fully coalesced, 1KiB/wave/instr) and select 4 dwords in registers.
// Misalignment r = idx & 3 is block-uniform -> scalar branch, no divergence.

constexpr int N_SAMPLES = 32768;
constexpr int NV = N_SAMPLES / 4;   // 8192 float4 per row
constexpr int BLOCK = 256;
constexpr int SPLIT = 4;            // blocks per row (TLP for latency hiding)
constexpr int VPB = NV / SPLIT;     // 2048 float4 per block

__global__ __launch_bounds__(BLOCK) void roll_place_kernel(
    const float* __restrict__ x,      // (B*C,)
    const float* __restrict__ clips,  // (B*C, N)
    float* __restrict__ out)          // (B*C, N)
{
    const int row = blockIdx.x >> 2;        // SPLIT = 4
    const int seg = blockIdx.x & (SPLIT - 1);

    // Truncation matches astype(int32); x*2^15 is exact in fp32.
    int idx = (int)(x[row] * (float)N_SAMPLES);
    idx = idx < 0 ? 0 : (idx > N_SAMPLES ? N_SAMPLES : idx);
    const int a = idx >> 2;                 // aligned float4 shift
    const int r = idx & 3;                  // dword misalignment (uniform)

    const float4* __restrict__ srcv =
        reinterpret_cast<const float4*>(clips + (size_t)row * N_SAMPLES);
    float4* __restrict__ dstv =
        reinterpret_cast<float4*>(out + (size_t)row * N_SAMPLES);
    const float* __restrict__ src = clips + (size_t)row * N_SAMPLES;

    const int v0 = seg * VPB;
    const int v1 = v0 + VPB;
    const int tid = threadIdx.x;

    if (r == 0) {
        // Pure aligned shift: one coalesced float4 load + store.
        #pragma unroll 4
        for (int v = v0 + tid; v < v1; v += BLOCK) {
            float4 o;
            if (v >= a) {
                o = srcv[v - a];
            } else {
                o = make_float4(0.f, 0.f, 0.f, 0.f);
            }
            dstv[v] = o;
        }
    } else {
        #pragma unroll 4
        for (int v = v0 + tid; v < v1; v += BLOCK) {
            float4 o;
            if (v > a) {
                // Bulk: two aligned, fully-coalesced float4 loads; select r.
                const float4 A  = srcv[v - a - 1];
                const float4 B4 = srcv[v - a];
                if (r == 1)      o = make_float4(A.w, B4.x, B4.y, B4.z);
                else if (r == 2) o = make_float4(A.z, A.w, B4.x, B4.y);
                else             o = make_float4(A.y, A.z, A.w, B4.x);
            } else if (v < a) {
                o = make_float4(0.f, 0.f, 0.f, 0.f);   // zero region, no load
            } else {
                // Boundary chunk (v == a): dword j -> j >= r ? src[j-r] : 0.
                float vals[4];
                #pragma unroll
                for (int j = 0; j < 4; ++j)
                    vals[j] = (j >= r) ? src[j - r] : 0.f;
                o = make_float4(vals[0], vals[1], vals[2], vals[3]);
            }
            dstv[v] = o;
        }
    }
}

extern "C" void kernel_launch(void* const* d_in, const int* in_sizes, int n_in,
                              void* d_out, int out_size, void* d_ws, size_t ws_size,
                              hipStream_t stream) {
    const float* x     = (const float*)d_in[0];  // (B, C) = 1024 positions
    const float* clips = (const float*)d_in[1];  // (B, C, N)
    // d_in[2] = actual, unused in forward.
    float* out = (float*)d_out;                  // (B, C, N) fp32

    const int rows = in_sizes[0];                // B*C = 1024
    roll_place_kernel<<<rows * SPLIT, BLOCK, 0, stream>>>(x, clips, out);
}

// Round 8
// 231.984 us; speedup vs baseline: 1.0101x; 1.0101x over previous
//
#include <hip/hip_runtime.h>

// RollScheduler forward: out[b,c,k] = clips[b,c,k-idx] for k>=idx else 0,
// idx = trunc(x[b,c] * N). Pure memory-bound shift-right per row.
// B=C=32, N=32768, fp32. `actual` input is unused in forward.
//
// R7 lesson: headline (232us) is harness-dominated (top-5 dispatches are all
// 512MiB poison fills @82us); our kernel is <81us. Coalescing change was
// byte-neutral (wave-union of scalar loads already consumed full lines).
// R8 probe: nontemporal stores -> output stream stops polluting L2/L3,
// matching the mechanism the 6.4TB/s harness fills use. Full unroll for MLP.

constexpr int N_SAMPLES = 32768;
constexpr int NV = N_SAMPLES / 4;   // 8192 float4 per row
constexpr int BLOCK = 256;
constexpr int SPLIT = 4;            // blocks per row
constexpr int VPB = NV / SPLIT;     // 2048 float4 per block
constexpr int ITERS = VPB / BLOCK;  // 8 per thread

typedef float v4f __attribute__((ext_vector_type(4)));

__global__ __launch_bounds__(BLOCK) void roll_place_kernel(
    const float* __restrict__ x,      // (B*C,)
    const float* __restrict__ clips,  // (B*C, N)
    float* __restrict__ out)          // (B*C, N)
{
    const int row = blockIdx.x >> 2;        // SPLIT = 4
    const int seg = blockIdx.x & (SPLIT - 1);

    // Truncation matches astype(int32); x*2^15 is exact in fp32.
    int idx = (int)(x[row] * (float)N_SAMPLES);
    idx = idx < 0 ? 0 : (idx > N_SAMPLES ? N_SAMPLES : idx);
    const int a = idx >> 2;                 // aligned float4 shift
    const int r = idx & 3;                  // dword misalignment (block-uniform)

    const v4f* __restrict__ srcv =
        reinterpret_cast<const v4f*>(clips + (size_t)row * N_SAMPLES);
    v4f* __restrict__ dstv =
        reinterpret_cast<v4f*>(out + (size_t)row * N_SAMPLES);
    const float* __restrict__ src = clips + (size_t)row * N_SAMPLES;

    const int v0 = seg * VPB;
    const int tid = threadIdx.x;
    const v4f zero = {0.f, 0.f, 0.f, 0.f};

    if (r == 0) {
        // Pure aligned shift: one coalesced float4 load + nontemporal store.
        #pragma unroll
        for (int i = 0; i < ITERS; ++i) {
            const int v = v0 + i * BLOCK + tid;
            v4f o = zero;
            if (v >= a) o = srcv[v - a];
            __builtin_nontemporal_store(o, &dstv[v]);
        }
    } else {
        #pragma unroll
        for (int i = 0; i < ITERS; ++i) {
            const int v = v0 + i * BLOCK + tid;
            v4f o;
            if (v > a) {
                // Bulk: two aligned, fully-coalesced float4 loads; select r.
                // Overlap between the two loads is L1-served (same lines).
                const v4f A = srcv[v - a - 1];
                const v4f B = srcv[v - a];
                if (r == 1)      o = (v4f){A.w, B.x, B.y, B.z};
                else if (r == 2) o = (v4f){A.z, A.w, B.x, B.y};
                else             o = (v4f){A.y, A.z, A.w, B.x};
            } else if (v < a) {
                o = zero;                              // zero region, no load
            } else {
                // Boundary chunk (v == a): dword j -> j >= r ? src[j-r] : 0.
                float vals[4];
                #pragma unroll
                for (int j = 0; j < 4; ++j)
                    vals[j] = (j >= r) ? src[j - r] : 0.f;
                o = (v4f){vals[0], vals[1], vals[2], vals[3]};
            }
            __builtin_nontemporal_store(o, &dstv[v]);
        }
    }
}

extern "C" void kernel_launch(void* const* d_in, const int* in_sizes, int n_in,
                              void* d_out, int out_size, void* d_ws, size_t ws_size,
                              hipStream_t stream) {
    const float* x     = (const float*)d_in[0];  // (B, C) = 1024 positions
    const float* clips = (const float*)d_in[1];  // (B, C, N)
    // d_in[2] = actual, unused in forward.
    float* out = (float*)d_out;                  // (B, C, N) fp32

    const int rows = in_sizes[0];                // B*C = 1024
    roll_place_kernel<<<rows * SPLIT, BLOCK, 0, stream>>>(x, clips, out);
}